// Round 1
// baseline (9434.813 us; speedup 1.0000x reference)
//
#include <hip/hip_runtime.h>
#include <math.h>

#define NPB   1024          // nodes per batch/event
#define NB    32            // batches
#define NTOT  (NPB * NB)    // 32768 nodes
#define KNN_K 30
#define FINF  __builtin_inff()

// ---------------------------------------------------------------------------
// node_pre: per node, as = (x@ (W1a-W1b) + b1)*s + t ;  vs = (x@W1b)*s ; sq = ||x||^2
// Edge-MLP layer 1 factorization: h_edge(i,j) = relu(as_i + vs_j).
// One wave per node (4 nodes / 256-thread block); lane = output channel.
// ---------------------------------------------------------------------------
template<int D>
__global__ __launch_bounds__(256)
void node_pre_kernel(const float* __restrict__ x, int lda,
                     const float* __restrict__ W1, const float* __restrict__ b1,
                     const float* __restrict__ s,  const float* __restrict__ t,
                     float* __restrict__ as_, float* __restrict__ vs_,
                     float* __restrict__ sq) {
  const int node = blockIdx.x * 4 + (threadIdx.x >> 6);
  const int c    = threadIdx.x & 63;
  const float* xr = x + (size_t)node * lda;
  float ap = b1[c], vv = 0.f;
  #pragma unroll
  for (int r = 0; r < D; ++r) {
    const float xv = xr[r];                   // wave-uniform row
    const float wa = W1[r * 64 + c];
    const float wb = W1[(D + r) * 64 + c];
    ap += xv * (wa - wb);
    vv += xv * wb;
  }
  const float sc = s[c], tc = t[c];
  as_[(size_t)node * 64 + c] = ap * sc + tc;
  vs_[(size_t)node * 64 + c] = vv * sc;
  // squared norm of x (wave reduction)
  float xv = (c < D) ? xr[c] : 0.f;
  float p = xv * xv;
  #pragma unroll
  for (int o = 32; o > 0; o >>= 1) p += __shfl_down(p, o);
  if (c == 0) sq[node] = p;
}

// ---------------------------------------------------------------------------
// knn: top-30 nearest (incl. self) in feature space, per query.
// 2 queries per wave, 8 per block. Query features in registers (all lanes hold
// the full query vector); lane L owns candidates L, L+64, ..., L+960 (16 slots,
// distances kept in registers). Selection: 30 rounds of local argmin over 16
// slots + 64-lane shfl reduce; winner's slot set to +inf. No LDS, no barriers.
// ---------------------------------------------------------------------------
template<int D>
__global__ __launch_bounds__(256)
void knn_kernel(const float* __restrict__ x, int lda,
                const float* __restrict__ sq, int* __restrict__ idx) {
  const int wave = threadIdx.x >> 6;
  const int lane = threadIdx.x & 63;
  const int q0   = blockIdx.x * 8 + wave * 2;
  const int nbase = q0 & ~(NPB - 1);          // first node of this batch

  float qa[D], qb[D];
  {
    const float* xq0 = x + (size_t)q0 * lda;
    const float* xq1 = xq0 + lda;
    #pragma unroll
    for (int r = 0; r < D; ++r) { qa[r] = xq0[r]; qb[r] = xq1[r]; }
  }
  const float sqa = sq[q0], sqb = sq[q0 + 1];

  float da[16], db[16];
  #pragma unroll
  for (int i = 0; i < 16; ++i) {
    const int j = nbase + lane + (i << 6);
    const float* xj = x + (size_t)j * lda;
    float d0 = 0.f, d1 = 0.f;
    if constexpr ((D & 3) == 0) {
      const float4* xj4 = (const float4*)xj;
      #pragma unroll
      for (int r4 = 0; r4 < D / 4; ++r4) {
        const float4 v = xj4[r4];
        d0 += qa[4*r4+0]*v.x + qa[4*r4+1]*v.y + qa[4*r4+2]*v.z + qa[4*r4+3]*v.w;
        d1 += qb[4*r4+0]*v.x + qb[4*r4+1]*v.y + qb[4*r4+2]*v.z + qb[4*r4+3]*v.w;
      }
    } else {
      #pragma unroll
      for (int r = 0; r < D; ++r) { const float xv = xj[r]; d0 += qa[r]*xv; d1 += qb[r]*xv; }
    }
    const float sj = sq[j];
    da[i] = sqa + sj - 2.f * d0;
    db[i] = sqb + sj - 2.f * d1;
  }

  auto select = [&](float (&d)[16], int qnode) {
    #pragma unroll 1
    for (int k = 0; k < KNN_K; ++k) {
      float best = d[0]; int bi = 0;
      #pragma unroll
      for (int i = 1; i < 16; ++i) { if (d[i] < best) { best = d[i]; bi = i; } }
      int bj = lane + (bi << 6);
      #pragma unroll
      for (int o = 32; o > 0; o >>= 1) {
        const float ov = __shfl_down(best, o);
        const int   oj = __shfl_down(bj, o);
        if (ov < best) { best = ov; bj = oj; }
      }
      bj = __shfl(bj, 0);
      if (lane == 0) idx[(size_t)qnode * KNN_K + k] = nbase + bj;
      #pragma unroll
      for (int i = 0; i < 16; ++i) if (bj == lane + (i << 6)) d[i] = FINF;  // remove winner
    }
  };
  select(da, q0);
  select(db, q0 + 1);
}

// ---------------------------------------------------------------------------
// edge: out[i][c] = max_k ( relu(as_i + vs_{j_k}) @ W2[:,c] ) + b2[c]
// 4 waves = 4 edge groups; lane = channel. W2 column held in registers.
// hbuf row is wave-private -> no __syncthreads in the edge loop.
// ---------------------------------------------------------------------------
__global__ __launch_bounds__(256)
void edge_kernel(const float* __restrict__ as_, const float* __restrict__ vs_,
                 const int* __restrict__ idx, const float* __restrict__ W2,
                 const float* __restrict__ b2,
                 float* __restrict__ xout, int ldc) {
  const int g = threadIdx.x >> 6;
  const int c = threadIdx.x & 63;
  float w2[64];
  #pragma unroll
  for (int r = 0; r < 64; ++r) w2[r] = W2[r * 64 + c];
  __shared__ float hbuf[4][64];
  __shared__ float mbuf[4][64];
  #pragma unroll 1
  for (int nn = 0; nn < 4; ++nn) {
    const int node = blockIdx.x * 4 + nn;
    const float av = as_[(size_t)node * 64 + c];
    float m = -FINF;
    #pragma unroll 1
    for (int tt = 0; tt < 8; ++tt) {
      const int k = tt * 4 + g;
      if (k < KNN_K) {                         // wave-uniform branch
        const int j = idx[(size_t)node * KNN_K + k];
        hbuf[g][c] = fmaxf(av + vs_[(size_t)j * 64 + c], 0.f);
        float acc = 0.f;
        const float4* h4 = (const float4*)hbuf[g];
        #pragma unroll
        for (int r4 = 0; r4 < 16; ++r4) {
          const float4 hv = h4[r4];
          acc += hv.x * w2[4*r4] + hv.y * w2[4*r4+1] + hv.z * w2[4*r4+2] + hv.w * w2[4*r4+3];
        }
        m = fmaxf(m, acc);
      }
    }
    mbuf[g][c] = m;
    __syncthreads();
    if (g == 0) {
      const float mm = fmaxf(fmaxf(mbuf[0][c], mbuf[1][c]), fmaxf(mbuf[2][c], mbuf[3][c]));
      xout[(size_t)node * ldc + c] = mm + b2[c];
    }
    __syncthreads();
  }
}

// ---------------------------------------------------------------------------
// fp32 tiled GEMM: C[M,N] = relu?(A[M,K] @ B[K,N] + bias), BM=128 BN=64 BK=16,
// 256 threads, 8x4 per-thread register tile. M%128==0, N%64==0, K%16==0.
// ---------------------------------------------------------------------------
template<bool RELU>
__global__ __launch_bounds__(256)
void gemm_kernel(const float* __restrict__ A, int lda,
                 const float* __restrict__ Bm, int ldb,
                 const float* __restrict__ bias,
                 float* __restrict__ C, int ldc, int K) {
  __shared__ float As[16][132];   // transposed A tile: As[k][m]
  __shared__ float Bs[16][68];
  const int tid = threadIdx.x;
  const int tn = tid & 15, tm = tid >> 4;
  const int m0 = tm * 8, n0 = tn * 4;
  const int bm = blockIdx.x * 128, bn = blockIdx.y * 64;
  float acc[8][4];
  #pragma unroll
  for (int i = 0; i < 8; ++i)
    #pragma unroll
    for (int j = 0; j < 4; ++j) acc[i][j] = 0.f;

  for (int k0 = 0; k0 < K; k0 += 16) {
    #pragma unroll
    for (int qd = 0; qd < 2; ++qd) {
      const int lin = tid * 2 + qd;           // 0..511 quads
      const int m = lin >> 2;
      const int kq = (lin & 3) * 4;
      const float4 v = *(const float4*)(A + (size_t)(bm + m) * lda + k0 + kq);
      As[kq + 0][m] = v.x; As[kq + 1][m] = v.y; As[kq + 2][m] = v.z; As[kq + 3][m] = v.w;
    }
    {
      const int k = tid >> 4;
      const int nq = (tid & 15) * 4;
      *(float4*)(&Bs[k][nq]) = *(const float4*)(Bm + (size_t)(k0 + k) * ldb + bn + nq);
    }
    __syncthreads();
    #pragma unroll
    for (int k = 0; k < 16; ++k) {
      const float4 a0 = *(const float4*)(&As[k][m0]);
      const float4 a1 = *(const float4*)(&As[k][m0 + 4]);
      const float4 bv = *(const float4*)(&Bs[k][n0]);
      const float av[8] = {a0.x, a0.y, a0.z, a0.w, a1.x, a1.y, a1.z, a1.w};
      const float bw[4] = {bv.x, bv.y, bv.z, bv.w};
      #pragma unroll
      for (int i = 0; i < 8; ++i)
        #pragma unroll
        for (int j = 0; j < 4; ++j) acc[i][j] += av[i] * bw[j];
    }
    __syncthreads();
  }
  #pragma unroll
  for (int i = 0; i < 8; ++i) {
    float4 r;
    r.x = acc[i][0] + bias[bn + n0 + 0];
    r.y = acc[i][1] + bias[bn + n0 + 1];
    r.z = acc[i][2] + bias[bn + n0 + 2];
    r.w = acc[i][3] + bias[bn + n0 + 3];
    if (RELU) {
      r.x = fmaxf(r.x, 0.f); r.y = fmaxf(r.y, 0.f);
      r.z = fmaxf(r.z, 0.f); r.w = fmaxf(r.w, 0.f);
    }
    *(float4*)(C + (size_t)(bm + m0 + i) * ldc + bn + n0) = r;
  }
}

// ---------------------------------------------------------------------------
// g4: logits = h3[row] @ W4[128,2] + b4 ; seg = log_softmax(logits). 1 wave/row.
// ---------------------------------------------------------------------------
__global__ __launch_bounds__(64)
void g4_kernel(const float* __restrict__ h3, const float* __restrict__ W4,
               const float* __restrict__ b4, float* __restrict__ seg) {
  const int row = blockIdx.x;
  const int lane = threadIdx.x;
  const float* hr = h3 + (size_t)row * 128;
  float p0 = 0.f, p1 = 0.f;
  #pragma unroll
  for (int h = 0; h < 2; ++h) {
    const int r = lane + h * 64;
    const float hv = hr[r];
    p0 += hv * W4[r * 2 + 0];
    p1 += hv * W4[r * 2 + 1];
  }
  #pragma unroll
  for (int o = 32; o > 0; o >>= 1) { p0 += __shfl_down(p0, o); p1 += __shfl_down(p1, o); }
  if (lane == 0) {
    const float l0 = p0 + b4[0], l1 = p1 + b4[1];
    const float mx = fmaxf(l0, l1);
    const float lse = mx + logf(expf(l0 - mx) + expf(l1 - mx));
    seg[(size_t)row * 2 + 0] = l0 - lse;
    seg[(size_t)row * 2 + 1] = l1 - lse;
  }
}

// ---------------------------------------------------------------------------
// wrapper: per event b: y = relu(flat @ mW1 + mb1) @ mW2 + mb2 ; log_softmax.
// ---------------------------------------------------------------------------
__global__ __launch_bounds__(256)
void wrapper_kernel(const float* __restrict__ seg, const float* __restrict__ W1,
                    const float* __restrict__ b1, const float* __restrict__ W2,
                    const float* __restrict__ b2, float* __restrict__ out) {
  __shared__ float fl[NPB * 2];
  __shared__ float y1[100];
  __shared__ float l2[2];
  const int b = blockIdx.x, tid = threadIdx.x;
  for (int i = tid; i < NPB * 2; i += 256) fl[i] = seg[(size_t)b * NPB * 2 + i];
  __syncthreads();
  if (tid < 100) {
    float acc = b1[tid];
    for (int r = 0; r < NPB * 2; ++r) acc += fl[r] * W1[(size_t)r * 100 + tid];
    y1[tid] = fmaxf(acc, 0.f);
  }
  __syncthreads();
  if (tid < 2) {
    float acc = b2[tid];
    for (int j = 0; j < 100; ++j) acc += y1[j] * W2[j * 2 + tid];
    l2[tid] = acc;
  }
  __syncthreads();
  if (tid == 0) {
    const float l0 = l2[0], l1 = l2[1];
    const float mx = fmaxf(l0, l1);
    const float lse = mx + logf(expf(l0 - mx) + expf(l1 - mx));
    out[b * 2 + 0] = l0 - lse;
    out[b * 2 + 1] = l1 - lse;
  }
}

// ---------------------------------------------------------------------------
extern "C" void kernel_launch(void* const* d_in, const int* in_sizes, int n_in,
                              void* d_out, int out_size, void* d_ws, size_t ws_size,
                              hipStream_t stream) {
  const float* pos   = (const float*)d_in[0];
  // d_in[1]=batch (uniform contiguous, unused), d_in[2]=batch_size (known)
  const float* c1_W1 = (const float*)d_in[3];
  const float* c1_b1 = (const float*)d_in[4];
  const float* c1_s  = (const float*)d_in[5];
  const float* c1_t  = (const float*)d_in[6];
  const float* c1_W2 = (const float*)d_in[7];
  const float* c1_b2 = (const float*)d_in[8];
  const float* c2_W1 = (const float*)d_in[9];
  const float* c2_b1 = (const float*)d_in[10];
  const float* c2_s  = (const float*)d_in[11];
  const float* c2_t  = (const float*)d_in[12];
  const float* c2_W2 = (const float*)d_in[13];
  const float* c2_b2 = (const float*)d_in[14];
  const float* c3_W1 = (const float*)d_in[15];
  const float* c3_b1 = (const float*)d_in[16];
  const float* c3_s  = (const float*)d_in[17];
  const float* c3_t  = (const float*)d_in[18];
  const float* c3_W2 = (const float*)d_in[19];
  const float* c3_b2 = (const float*)d_in[20];
  const float* h_W1  = (const float*)d_in[21];
  const float* h_b1  = (const float*)d_in[22];
  const float* h_W2  = (const float*)d_in[23];
  const float* h_b2  = (const float*)d_in[24];
  const float* h_W3  = (const float*)d_in[25];
  const float* h_b3  = (const float*)d_in[26];
  const float* h_W4  = (const float*)d_in[27];
  const float* h_b4  = (const float*)d_in[28];
  const float* m_W1  = (const float*)d_in[29];
  const float* m_b1  = (const float*)d_in[30];
  const float* m_W2  = (const float*)d_in[31];
  const float* m_b2  = (const float*)d_in[32];

  float* ws = (float*)d_ws;
  size_t off = 0;
  auto alloc = [&](size_t n) {
    float* p = ws + off;
    off += (n + 63) & ~(size_t)63;              // 256 B alignment
    return p;
  };
  float* xfeat = alloc((size_t)NTOT * 192);     // x1 | x2 | x3 columns
  int*   idx   = (int*)alloc((size_t)NTOT * KNN_K);
  float* asb   = alloc((size_t)NTOT * 64);
  float* vsb   = alloc((size_t)NTOT * 64);
  float* sqb   = alloc(NTOT);
  float* seg   = alloc((size_t)NTOT * 2);
  // head chunking to fit workspace: per chunk-row 1024+256+128 floats
  const size_t totf = ws_size / 4;
  const size_t avail = (totf > off) ? (totf - off) : 0;
  int CH = 1;
  while (CH < 256 && ((size_t)(NTOT / CH) * 1408 + 1024) > avail) CH <<= 1;
  const int CR = NTOT / CH;
  float* h1 = alloc((size_t)CR * 1024);
  float* h2 = alloc((size_t)CR * 256);
  float* h3 = alloc((size_t)CR * 128);

  // ---- conv1 (input pos, D=7) -> xfeat cols 0..63
  node_pre_kernel<7><<<NTOT / 4, 256, 0, stream>>>(pos, 7, c1_W1, c1_b1, c1_s, c1_t, asb, vsb, sqb);
  knn_kernel<7><<<NTOT / 8, 256, 0, stream>>>(pos, 7, sqb, idx);
  edge_kernel<<<NTOT / 4, 256, 0, stream>>>(asb, vsb, idx, c1_W2, c1_b2, xfeat + 0, 192);
  // ---- conv2 (input x1, D=64) -> cols 64..127
  node_pre_kernel<64><<<NTOT / 4, 256, 0, stream>>>(xfeat + 0, 192, c2_W1, c2_b1, c2_s, c2_t, asb, vsb, sqb);
  knn_kernel<64><<<NTOT / 8, 256, 0, stream>>>(xfeat + 0, 192, sqb, idx);
  edge_kernel<<<NTOT / 4, 256, 0, stream>>>(asb, vsb, idx, c2_W2, c2_b2, xfeat + 64, 192);
  // ---- conv3 (input x2, D=64) -> cols 128..191
  node_pre_kernel<64><<<NTOT / 4, 256, 0, stream>>>(xfeat + 64, 192, c3_W1, c3_b1, c3_s, c3_t, asb, vsb, sqb);
  knn_kernel<64><<<NTOT / 8, 256, 0, stream>>>(xfeat + 64, 192, sqb, idx);
  edge_kernel<<<NTOT / 4, 256, 0, stream>>>(asb, vsb, idx, c3_W2, c3_b2, xfeat + 128, 192);

  // ---- head MLP (chunked over nodes) + per-node log_softmax
  for (int ch = 0; ch < CH; ++ch) {
    const float* Ax = xfeat + (size_t)ch * CR * 192;
    gemm_kernel<true><<<dim3(CR / 128, 16), 256, 0, stream>>>(Ax, 192, h_W1, 1024, h_b1, h1, 1024, 192);
    gemm_kernel<true><<<dim3(CR / 128, 4),  256, 0, stream>>>(h1, 1024, h_W2, 256, h_b2, h2, 256, 1024);
    gemm_kernel<true><<<dim3(CR / 128, 2),  256, 0, stream>>>(h2, 256, h_W3, 128, h_b3, h3, 128, 256);
    g4_kernel<<<CR, 64, 0, stream>>>(h3, h_W4, h_b4, seg + (size_t)ch * CR * 2);
  }

  // ---- wrapper MLP per event
  wrapper_kernel<<<NB, 256, 0, stream>>>(seg, m_W1, m_b1, m_W2, m_b2, (float*)d_out);
}

// Round 2
// 1894.825 us; speedup vs baseline: 4.9793x; 4.9793x over previous
//
#include <hip/hip_runtime.h>
#include <math.h>

#define NPB   1024          // nodes per batch/event
#define NB    32            // batches
#define NTOT  (NPB * NB)    // 32768 nodes
#define KNN_K 30
#define FINF  __builtin_inff()

// ---------------------------------------------------------------------------
// node_pre: per node, as = (x@(W1a-W1b) + b1)*s + t ;  vs = (x@W1b)*s ; sq = ||x||^2
// Edge-MLP layer 1 factorization: h_edge(i,j) = relu(as_i + vs_j).
// One wave per node (4 nodes / 256-thread block); lane = output channel.
// ---------------------------------------------------------------------------
template<int D>
__global__ __launch_bounds__(256)
void node_pre_kernel(const float* __restrict__ x, int lda,
                     const float* __restrict__ W1, const float* __restrict__ b1,
                     const float* __restrict__ s,  const float* __restrict__ t,
                     float* __restrict__ as_, float* __restrict__ vs_,
                     float* __restrict__ sq) {
  const int node = blockIdx.x * 4 + (threadIdx.x >> 6);
  const int c    = threadIdx.x & 63;
  const float* xr = x + (size_t)node * lda;
  float ap = b1[c], vv = 0.f;
  #pragma unroll
  for (int r = 0; r < D; ++r) {
    const float xv = xr[r];                   // wave-uniform row
    const float wa = W1[r * 64 + c];
    const float wb = W1[(D + r) * 64 + c];
    ap += xv * (wa - wb);
    vv += xv * wb;
  }
  const float sc = s[c], tc = t[c];
  as_[(size_t)node * 64 + c] = ap * sc + tc;
  vs_[(size_t)node * 64 + c] = vv * sc;
  // squared norm of x (wave reduction)
  float xv = (c < D) ? xr[c] : 0.f;
  float p = xv * xv;
  #pragma unroll
  for (int o = 32; o > 0; o >>= 1) p += __shfl_down(p, o);
  if (c == 0) sq[node] = p;
}

// ---------------------------------------------------------------------------
// dist: per (batch, 64x64 tile) compute D2[i][j] = sq_i + sq_j - 2 x_i.x_j.
// Standard LDS-tiled GEMM, 256 threads, 4x4 register tile per thread.
// Grid: (16, 16, NBC batches); d2 buffer is [NBC][1024][1024].
// ---------------------------------------------------------------------------
template<int D>
__global__ __launch_bounds__(256)
void dist_kernel(const float* __restrict__ x, int lda,
                 const float* __restrict__ sq,
                 float* __restrict__ d2, int b0) {
  constexpr int PAD = (D == 64) ? 68 : 8;   // 68*4B=272B rows -> 16B-aligned float4
  __shared__ float Xa[64][PAD];
  __shared__ float Xb[64][PAD];
  __shared__ float sqa[64], sqb[64];
  const int nbase = (b0 + blockIdx.z) * NPB;
  const int i0 = blockIdx.x * 64, j0 = blockIdx.y * 64;
  const int tid = threadIdx.x;

  if constexpr (D == 64) {
    #pragma unroll
    for (int p = 0; p < 4; ++p) {
      const int row = (tid >> 4) + p * 16;
      const int c4 = (tid & 15) * 4;
      const float4 va = *(const float4*)(x + (size_t)(nbase + i0 + row) * lda + c4);
      Xa[row][c4 + 0] = va.x; Xa[row][c4 + 1] = va.y;
      Xa[row][c4 + 2] = va.z; Xa[row][c4 + 3] = va.w;
      const float4 vb = *(const float4*)(x + (size_t)(nbase + j0 + row) * lda + c4);
      Xb[row][c4 + 0] = vb.x; Xb[row][c4 + 1] = vb.y;
      Xb[row][c4 + 2] = vb.z; Xb[row][c4 + 3] = vb.w;
    }
  } else {
    // lda == D (contiguous rows): linear copy
    for (int i = tid; i < 64 * D; i += 256) {
      Xa[i / D][i % D] = x[(size_t)(nbase + i0) * lda + i];
      Xb[i / D][i % D] = x[(size_t)(nbase + j0) * lda + i];
    }
  }
  if (tid < 64) sqa[tid] = sq[nbase + i0 + tid];
  else if (tid < 128) sqb[tid - 64] = sq[nbase + j0 + tid - 64];
  __syncthreads();

  const int ti = tid >> 4, tj = tid & 15;
  float acc[4][4];
  #pragma unroll
  for (int u = 0; u < 4; ++u)
    #pragma unroll
    for (int v = 0; v < 4; ++v) acc[u][v] = 0.f;

  if constexpr (D == 64) {
    #pragma unroll
    for (int d4 = 0; d4 < 16; ++d4) {
      float4 a4[4], b4[4];
      #pragma unroll
      for (int u = 0; u < 4; ++u) a4[u] = *(const float4*)(&Xa[ti * 4 + u][d4 * 4]);
      #pragma unroll
      for (int v = 0; v < 4; ++v) b4[v] = *(const float4*)(&Xb[tj * 4 + v][d4 * 4]);
      #pragma unroll
      for (int u = 0; u < 4; ++u)
        #pragma unroll
        for (int v = 0; v < 4; ++v)
          acc[u][v] += a4[u].x * b4[v].x + a4[u].y * b4[v].y
                     + a4[u].z * b4[v].z + a4[u].w * b4[v].w;
    }
  } else {
    #pragma unroll
    for (int d = 0; d < D; ++d) {
      float a[4], b[4];
      #pragma unroll
      for (int u = 0; u < 4; ++u) a[u] = Xa[ti * 4 + u][d];
      #pragma unroll
      for (int v = 0; v < 4; ++v) b[v] = Xb[tj * 4 + v][d];
      #pragma unroll
      for (int u = 0; u < 4; ++u)
        #pragma unroll
        for (int v = 0; v < 4; ++v) acc[u][v] += a[u] * b[v];
    }
  }

  #pragma unroll
  for (int u = 0; u < 4; ++u) {
    const float si = sqa[ti * 4 + u];
    float4 r;
    r.x = si + sqb[tj * 4 + 0] - 2.f * acc[u][0];
    r.y = si + sqb[tj * 4 + 1] - 2.f * acc[u][1];
    r.z = si + sqb[tj * 4 + 2] - 2.f * acc[u][2];
    r.w = si + sqb[tj * 4 + 3] - 2.f * acc[u][3];
    *(float4*)(d2 + ((size_t)blockIdx.z * NPB + i0 + ti * 4 + u) * NPB + j0 + tj * 4) = r;
  }
}

// ---------------------------------------------------------------------------
// select: top-30 smallest per D2 row. One wave per query; lane L owns slots
// L+64i (16 regs); 30 rounds of local argmin + shfl reduce. Coalesced row read.
// ---------------------------------------------------------------------------
__global__ __launch_bounds__(256)
void select_kernel(const float* __restrict__ d2, int b0, int* __restrict__ idx) {
  const int wave = threadIdx.x >> 6, lane = threadIdx.x & 63;
  const int ql = blockIdx.x * 4 + wave;         // row within chunk
  const int bl = ql >> 10;                      // chunk-local batch
  const int qnode = (b0 + bl) * NPB + (ql & (NPB - 1));
  const float* row = d2 + (size_t)ql * NPB;
  float d[16];
  #pragma unroll
  for (int i = 0; i < 16; ++i) d[i] = row[lane + (i << 6)];
  int* out = idx + (size_t)qnode * KNN_K;
  const int jbase = (b0 + bl) * NPB;
  #pragma unroll 1
  for (int k = 0; k < KNN_K; ++k) {
    float best = d[0]; int bi = 0;
    #pragma unroll
    for (int i = 1; i < 16; ++i) if (d[i] < best) { best = d[i]; bi = i; }
    int bj = lane + (bi << 6);
    #pragma unroll
    for (int o = 32; o > 0; o >>= 1) {
      const float ov = __shfl_down(best, o);
      const int   oj = __shfl_down(bj, o);
      if (ov < best) { best = ov; bj = oj; }
    }
    bj = __shfl(bj, 0);
    if (lane == 0) out[k] = jbase + bj;
    #pragma unroll
    for (int i = 0; i < 16; ++i) if (bj == lane + (i << 6)) d[i] = FINF;
  }
}

// ---------------------------------------------------------------------------
// edge: out[i][c] = max_k ( relu(as_i + vs_{j_k}) @ W2[:,c] ) + b2[c]
// 4 waves = 4 edge groups; lane = channel. W2 column in registers.
// Two-phase per node: write all 8 h-rows (loads pipeline), then dot all 8.
// hbuf rows are wave-private -> no syncthreads in the edge loop.
// ---------------------------------------------------------------------------
__global__ __launch_bounds__(256)
void edge_kernel(const float* __restrict__ as_, const float* __restrict__ vs_,
                 const int* __restrict__ idx, const float* __restrict__ W2,
                 const float* __restrict__ b2,
                 float* __restrict__ xout, int ldc) {
  const int g = threadIdx.x >> 6;
  const int c = threadIdx.x & 63;
  float w2[64];
  #pragma unroll
  for (int r = 0; r < 64; ++r) w2[r] = W2[r * 64 + c];
  __shared__ float hbuf[4][8][64];
  __shared__ float mbuf[4][64];
  #pragma unroll 1
  for (int nn = 0; nn < 4; ++nn) {
    const int node = blockIdx.x * 4 + nn;
    const float av = as_[(size_t)node * 64 + c];
    const int* nidx = idx + (size_t)node * KNN_K;
    // phase 1: gather + first layer for this wave's 8 edges
    #pragma unroll
    for (int tt = 0; tt < 8; ++tt) {
      const int k = tt * 4 + g;
      if (k < KNN_K) {                         // wave-uniform branch
        const int j = nidx[k];
        hbuf[g][tt][c] = fmaxf(av + vs_[(size_t)j * 64 + c], 0.f);
      }
    }
    // phase 2: second layer + max over this wave's edges
    float m = -FINF;
    #pragma unroll
    for (int tt = 0; tt < 8; ++tt) {
      const int k = tt * 4 + g;
      if (k < KNN_K) {
        float acc = 0.f;
        const float4* h4 = (const float4*)hbuf[g][tt];
        #pragma unroll
        for (int r4 = 0; r4 < 16; ++r4) {
          const float4 hv = h4[r4];
          acc += hv.x * w2[4*r4] + hv.y * w2[4*r4+1] + hv.z * w2[4*r4+2] + hv.w * w2[4*r4+3];
        }
        m = fmaxf(m, acc);
      }
    }
    mbuf[g][c] = m;
    __syncthreads();
    if (g == 0) {
      const float mm = fmaxf(fmaxf(mbuf[0][c], mbuf[1][c]), fmaxf(mbuf[2][c], mbuf[3][c]));
      xout[(size_t)node * ldc + c] = mm + b2[c];
    }
    __syncthreads();
  }
}

// ---------------------------------------------------------------------------
// fp32 tiled GEMM: C[M,N] = relu?(A[M,K] @ B[K,N] + bias), BM=128 BN=64 BK=16,
// 256 threads, 8x4 per-thread register tile. M%128==0, N%64==0, K%16==0.
// ---------------------------------------------------------------------------
template<bool RELU>
__global__ __launch_bounds__(256)
void gemm_kernel(const float* __restrict__ A, int lda,
                 const float* __restrict__ Bm, int ldb,
                 const float* __restrict__ bias,
                 float* __restrict__ C, int ldc, int K) {
  __shared__ float As[16][132];   // transposed A tile: As[k][m]
  __shared__ float Bs[16][68];
  const int tid = threadIdx.x;
  const int tn = tid & 15, tm = tid >> 4;
  const int m0 = tm * 8, n0 = tn * 4;
  const int bm = blockIdx.x * 128, bn = blockIdx.y * 64;
  float acc[8][4];
  #pragma unroll
  for (int i = 0; i < 8; ++i)
    #pragma unroll
    for (int j = 0; j < 4; ++j) acc[i][j] = 0.f;

  for (int k0 = 0; k0 < K; k0 += 16) {
    #pragma unroll
    for (int qd = 0; qd < 2; ++qd) {
      const int lin = tid * 2 + qd;           // 0..511 quads
      const int m = lin >> 2;
      const int kq = (lin & 3) * 4;
      const float4 v = *(const float4*)(A + (size_t)(bm + m) * lda + k0 + kq);
      As[kq + 0][m] = v.x; As[kq + 1][m] = v.y; As[kq + 2][m] = v.z; As[kq + 3][m] = v.w;
    }
    {
      const int k = tid >> 4;
      const int nq = (tid & 15) * 4;
      *(float4*)(&Bs[k][nq]) = *(const float4*)(Bm + (size_t)(k0 + k) * ldb + bn + nq);
    }
    __syncthreads();
    #pragma unroll
    for (int k = 0; k < 16; ++k) {
      const float4 a0 = *(const float4*)(&As[k][m0]);
      const float4 a1 = *(const float4*)(&As[k][m0 + 4]);
      const float4 bv = *(const float4*)(&Bs[k][n0]);
      const float av[8] = {a0.x, a0.y, a0.z, a0.w, a1.x, a1.y, a1.z, a1.w};
      const float bw[4] = {bv.x, bv.y, bv.z, bv.w};
      #pragma unroll
      for (int i = 0; i < 8; ++i)
        #pragma unroll
        for (int j = 0; j < 4; ++j) acc[i][j] += av[i] * bw[j];
    }
    __syncthreads();
  }
  #pragma unroll
  for (int i = 0; i < 8; ++i) {
    float4 r;
    r.x = acc[i][0] + bias[bn + n0 + 0];
    r.y = acc[i][1] + bias[bn + n0 + 1];
    r.z = acc[i][2] + bias[bn + n0 + 2];
    r.w = acc[i][3] + bias[bn + n0 + 3];
    if (RELU) {
      r.x = fmaxf(r.x, 0.f); r.y = fmaxf(r.y, 0.f);
      r.z = fmaxf(r.z, 0.f); r.w = fmaxf(r.w, 0.f);
    }
    *(float4*)(C + (size_t)(bm + m0 + i) * ldc + bn + n0) = r;
  }
}

// ---------------------------------------------------------------------------
// g4: logits = h3[row] @ W4[128,2] + b4 ; seg = log_softmax(logits). 1 wave/row.
// ---------------------------------------------------------------------------
__global__ __launch_bounds__(64)
void g4_kernel(const float* __restrict__ h3, const float* __restrict__ W4,
               const float* __restrict__ b4, float* __restrict__ seg) {
  const int row = blockIdx.x;
  const int lane = threadIdx.x;
  const float* hr = h3 + (size_t)row * 128;
  float p0 = 0.f, p1 = 0.f;
  #pragma unroll
  for (int h = 0; h < 2; ++h) {
    const int r = lane + h * 64;
    const float hv = hr[r];
    p0 += hv * W4[r * 2 + 0];
    p1 += hv * W4[r * 2 + 1];
  }
  #pragma unroll
  for (int o = 32; o > 0; o >>= 1) { p0 += __shfl_down(p0, o); p1 += __shfl_down(p1, o); }
  if (lane == 0) {
    const float l0 = p0 + b4[0], l1 = p1 + b4[1];
    const float mx = fmaxf(l0, l1);
    const float lse = mx + logf(expf(l0 - mx) + expf(l1 - mx));
    seg[(size_t)row * 2 + 0] = l0 - lse;
    seg[(size_t)row * 2 + 1] = l1 - lse;
  }
}

// ---------------------------------------------------------------------------
// wrapper: per event b: y = relu(flat @ mW1 + mb1) @ mW2 + mb2 ; log_softmax.
// ---------------------------------------------------------------------------
__global__ __launch_bounds__(256)
void wrapper_kernel(const float* __restrict__ seg, const float* __restrict__ W1,
                    const float* __restrict__ b1, const float* __restrict__ W2,
                    const float* __restrict__ b2, float* __restrict__ out) {
  __shared__ float fl[NPB * 2];
  __shared__ float y1[100];
  __shared__ float l2[2];
  const int b = blockIdx.x, tid = threadIdx.x;
  for (int i = tid; i < NPB * 2; i += 256) fl[i] = seg[(size_t)b * NPB * 2 + i];
  __syncthreads();
  if (tid < 100) {
    float acc = b1[tid];
    for (int r = 0; r < NPB * 2; ++r) acc += fl[r] * W1[(size_t)r * 100 + tid];
    y1[tid] = fmaxf(acc, 0.f);
  }
  __syncthreads();
  if (tid < 2) {
    float acc = b2[tid];
    for (int j = 0; j < 100; ++j) acc += y1[j] * W2[j * 2 + tid];
    l2[tid] = acc;
  }
  __syncthreads();
  if (tid == 0) {
    const float l0 = l2[0], l1 = l2[1];
    const float mx = fmaxf(l0, l1);
    const float lse = mx + logf(expf(l0 - mx) + expf(l1 - mx));
    out[b * 2 + 0] = l0 - lse;
    out[b * 2 + 1] = l1 - lse;
  }
}

// ---------------------------------------------------------------------------
extern "C" void kernel_launch(void* const* d_in, const int* in_sizes, int n_in,
                              void* d_out, int out_size, void* d_ws, size_t ws_size,
                              hipStream_t stream) {
  const float* pos   = (const float*)d_in[0];
  // d_in[1]=batch (uniform contiguous, unused), d_in[2]=batch_size (known)
  const float* c1_W1 = (const float*)d_in[3];
  const float* c1_b1 = (const float*)d_in[4];
  const float* c1_s  = (const float*)d_in[5];
  const float* c1_t  = (const float*)d_in[6];
  const float* c1_W2 = (const float*)d_in[7];
  const float* c1_b2 = (const float*)d_in[8];
  const float* c2_W1 = (const float*)d_in[9];
  const float* c2_b1 = (const float*)d_in[10];
  const float* c2_s  = (const float*)d_in[11];
  const float* c2_t  = (const float*)d_in[12];
  const float* c2_W2 = (const float*)d_in[13];
  const float* c2_b2 = (const float*)d_in[14];
  const float* c3_W1 = (const float*)d_in[15];
  const float* c3_b1 = (const float*)d_in[16];
  const float* c3_s  = (const float*)d_in[17];
  const float* c3_t  = (const float*)d_in[18];
  const float* c3_W2 = (const float*)d_in[19];
  const float* c3_b2 = (const float*)d_in[20];
  const float* h_W1  = (const float*)d_in[21];
  const float* h_b1  = (const float*)d_in[22];
  const float* h_W2  = (const float*)d_in[23];
  const float* h_b2  = (const float*)d_in[24];
  const float* h_W3  = (const float*)d_in[25];
  const float* h_b3  = (const float*)d_in[26];
  const float* h_W4  = (const float*)d_in[27];
  const float* h_b4  = (const float*)d_in[28];
  const float* m_W1  = (const float*)d_in[29];
  const float* m_b1  = (const float*)d_in[30];
  const float* m_W2  = (const float*)d_in[31];
  const float* m_b2  = (const float*)d_in[32];

  float* ws = (float*)d_ws;
  size_t off = 0;
  auto alloc = [&](size_t n) {
    float* p = ws + off;
    off += (n + 63) & ~(size_t)63;              // 256 B alignment
    return p;
  };
  float* xfeat = alloc((size_t)NTOT * 192);     // x1 | x2 | x3 columns
  int*   idx   = (int*)alloc((size_t)NTOT * KNN_K);
  float* asb   = alloc((size_t)NTOT * 64);
  float* vsb   = alloc((size_t)NTOT * 64);
  float* sqb   = alloc(NTOT);
  float* seg   = alloc((size_t)NTOT * 2);

  // Union region: d2 (knn phase) aliases h1/h2/h3 (head phase) — disjoint in time.
  const size_t totf = ws_size / 4;
  const size_t avail = (totf > off + 1024) ? (totf - off - 1024) : 0;
  int NBC = 32;                                  // batches per dist/select chunk
  while (NBC > 1 && (size_t)NBC * NPB * NPB > avail) NBC >>= 1;
  int CH = 1;                                    // head node-chunks
  while (CH < 256 && (size_t)(NTOT / CH) * 1408 > avail) CH <<= 1;
  const int CR = NTOT / CH;
  float* d2buf = alloc(0);                       // start of union region
  float* h1 = d2buf;
  float* h2 = h1 + (size_t)CR * 1024;
  float* h3 = h2 + (size_t)CR * 256;

  auto run_knn = [&](const float* x, int lda, int D) {
    for (int b0 = 0; b0 < NB; b0 += NBC) {
      if (D == 7) {
        dist_kernel<7><<<dim3(16, 16, NBC), 256, 0, stream>>>(x, lda, sqb, d2buf, b0);
      } else {
        dist_kernel<64><<<dim3(16, 16, NBC), 256, 0, stream>>>(x, lda, sqb, d2buf, b0);
      }
      select_kernel<<<(NBC * NPB) / 4, 256, 0, stream>>>(d2buf, b0, idx);
    }
  };

  // ---- conv1 (input pos, D=7) -> xfeat cols 0..63
  node_pre_kernel<7><<<NTOT / 4, 256, 0, stream>>>(pos, 7, c1_W1, c1_b1, c1_s, c1_t, asb, vsb, sqb);
  run_knn(pos, 7, 7);
  edge_kernel<<<NTOT / 4, 256, 0, stream>>>(asb, vsb, idx, c1_W2, c1_b2, xfeat + 0, 192);
  // ---- conv2 (input x1, D=64) -> cols 64..127
  node_pre_kernel<64><<<NTOT / 4, 256, 0, stream>>>(xfeat + 0, 192, c2_W1, c2_b1, c2_s, c2_t, asb, vsb, sqb);
  run_knn(xfeat + 0, 192, 64);
  edge_kernel<<<NTOT / 4, 256, 0, stream>>>(asb, vsb, idx, c2_W2, c2_b2, xfeat + 64, 192);
  // ---- conv3 (input x2, D=64) -> cols 128..191
  node_pre_kernel<64><<<NTOT / 4, 256, 0, stream>>>(xfeat + 64, 192, c3_W1, c3_b1, c3_s, c3_t, asb, vsb, sqb);
  run_knn(xfeat + 64, 192, 64);
  edge_kernel<<<NTOT / 4, 256, 0, stream>>>(asb, vsb, idx, c3_W2, c3_b2, xfeat + 128, 192);

  // ---- head MLP (chunked over nodes) + per-node log_softmax
  for (int ch = 0; ch < CH; ++ch) {
    const float* Ax = xfeat + (size_t)ch * CR * 192;
    gemm_kernel<true><<<dim3(CR / 128, 16), 256, 0, stream>>>(Ax, 192, h_W1, 1024, h_b1, h1, 1024, 192);
    gemm_kernel<true><<<dim3(CR / 128, 4),  256, 0, stream>>>(h1, 1024, h_W2, 256, h_b2, h2, 256, 1024);
    gemm_kernel<true><<<dim3(CR / 128, 2),  256, 0, stream>>>(h2, 256, h_W3, 128, h_b3, h3, 128, 256);
    g4_kernel<<<CR, 64, 0, stream>>>(h3, h_W4, h_b4, seg + (size_t)ch * CR * 2);
  }

  // ---- wrapper MLP per event
  wrapper_kernel<<<NB, 256, 0, stream>>>(seg, m_W1, m_b1, m_W2, m_b2, (float*)d_out);
}

// Round 3
// 1112.323 us; speedup vs baseline: 8.4821x; 1.7035x over previous
//
#include <hip/hip_runtime.h>
#include <math.h>

#define NPB   1024          // nodes per batch/event
#define NB    32            // batches
#define NTOT  (NPB * NB)    // 32768 nodes
#define KNN_K 30
#define FINF  __builtin_inff()

typedef __attribute__((ext_vector_type(8))) short bf16x8;
typedef __attribute__((ext_vector_type(4))) float f32x4;
typedef unsigned short ushort_t;

__device__ inline ushort_t f2bf(float f) {          // RNE f32 -> bf16
  unsigned u = __builtin_bit_cast(unsigned, f);
  u += 0x7FFFu + ((u >> 16) & 1u);
  return (ushort_t)(u >> 16);
}
__device__ inline float bf2f(ushort_t h) {
  return __builtin_bit_cast(float, (unsigned)h << 16);
}

// ---------------------------------------------------------------------------
// node_pre: as = (x@(W1a-W1b)+b1)*s+t ; vs = (x@W1b)*s ; sq = ||x||^2 (f32).
// as/vs stored bf16 (consumed by MFMA edge kernel); sq stays f32 (kNN exact).
// One wave per node; lane = output channel.
// ---------------------------------------------------------------------------
template<int D>
__global__ __launch_bounds__(256)
void node_pre_kernel(const float* __restrict__ x, int lda,
                     const float* __restrict__ W1, const float* __restrict__ b1,
                     const float* __restrict__ s,  const float* __restrict__ t,
                     ushort_t* __restrict__ as_, ushort_t* __restrict__ vs_,
                     float* __restrict__ sq) {
  const int node = blockIdx.x * 4 + (threadIdx.x >> 6);
  const int c    = threadIdx.x & 63;
  const float* xr = x + (size_t)node * lda;
  float ap = b1[c], vv = 0.f;
  #pragma unroll
  for (int r = 0; r < D; ++r) {
    const float xv = xr[r];                   // wave-uniform row
    const float wa = W1[r * 64 + c];
    const float wb = W1[(D + r) * 64 + c];
    ap += xv * (wa - wb);
    vv += xv * wb;
  }
  const float sc = s[c], tc = t[c];
  as_[(size_t)node * 64 + c] = f2bf(ap * sc + tc);
  vs_[(size_t)node * 64 + c] = f2bf(vv * sc);
  float xv = (c < D) ? xr[c] : 0.f;
  float p = xv * xv;
  #pragma unroll
  for (int o = 32; o > 0; o >>= 1) p += __shfl_down(p, o);
  if (c == 0) sq[node] = p;
}

// ---------------------------------------------------------------------------
// dist: per (batch, 64x64 tile) D2[i][j] = sq_i + sq_j - 2 x_i.x_j. Pure fp32
// (kNN selection must not be perturbed). LDS-tiled, 4x4 register blocking.
// ---------------------------------------------------------------------------
template<int D>
__global__ __launch_bounds__(256)
void dist_kernel(const float* __restrict__ x, int lda,
                 const float* __restrict__ sq,
                 float* __restrict__ d2, int b0) {
  constexpr int PAD = (D == 64) ? 68 : 8;
  __shared__ float Xa[64][PAD];
  __shared__ float Xb[64][PAD];
  __shared__ float sqa[64], sqb[64];
  const int nbase = (b0 + blockIdx.z) * NPB;
  const int i0 = blockIdx.x * 64, j0 = blockIdx.y * 64;
  const int tid = threadIdx.x;

  if constexpr (D == 64) {
    #pragma unroll
    for (int p = 0; p < 4; ++p) {
      const int row = (tid >> 4) + p * 16;
      const int c4 = (tid & 15) * 4;
      const float4 va = *(const float4*)(x + (size_t)(nbase + i0 + row) * lda + c4);
      Xa[row][c4 + 0] = va.x; Xa[row][c4 + 1] = va.y;
      Xa[row][c4 + 2] = va.z; Xa[row][c4 + 3] = va.w;
      const float4 vb = *(const float4*)(x + (size_t)(nbase + j0 + row) * lda + c4);
      Xb[row][c4 + 0] = vb.x; Xb[row][c4 + 1] = vb.y;
      Xb[row][c4 + 2] = vb.z; Xb[row][c4 + 3] = vb.w;
    }
  } else {
    for (int i = tid; i < 64 * D; i += 256) {
      Xa[i / D][i % D] = x[(size_t)(nbase + i0) * lda + i];
      Xb[i / D][i % D] = x[(size_t)(nbase + j0) * lda + i];
    }
  }
  if (tid < 64) sqa[tid] = sq[nbase + i0 + tid];
  else if (tid < 128) sqb[tid - 64] = sq[nbase + j0 + tid - 64];
  __syncthreads();

  const int ti = tid >> 4, tj = tid & 15;
  float acc[4][4];
  #pragma unroll
  for (int u = 0; u < 4; ++u)
    #pragma unroll
    for (int v = 0; v < 4; ++v) acc[u][v] = 0.f;

  if constexpr (D == 64) {
    #pragma unroll
    for (int d4 = 0; d4 < 16; ++d4) {
      float4 a4[4], b4[4];
      #pragma unroll
      for (int u = 0; u < 4; ++u) a4[u] = *(const float4*)(&Xa[ti * 4 + u][d4 * 4]);
      #pragma unroll
      for (int v = 0; v < 4; ++v) b4[v] = *(const float4*)(&Xb[tj * 4 + v][d4 * 4]);
      #pragma unroll
      for (int u = 0; u < 4; ++u)
        #pragma unroll
        for (int v = 0; v < 4; ++v)
          acc[u][v] += a4[u].x * b4[v].x + a4[u].y * b4[v].y
                     + a4[u].z * b4[v].z + a4[u].w * b4[v].w;
    }
  } else {
    #pragma unroll
    for (int d = 0; d < D; ++d) {
      float a[4], b[4];
      #pragma unroll
      for (int u = 0; u < 4; ++u) a[u] = Xa[ti * 4 + u][d];
      #pragma unroll
      for (int v = 0; v < 4; ++v) b[v] = Xb[tj * 4 + v][d];
      #pragma unroll
      for (int u = 0; u < 4; ++u)
        #pragma unroll
        for (int v = 0; v < 4; ++v) acc[u][v] += a[u] * b[v];
    }
  }

  #pragma unroll
  for (int u = 0; u < 4; ++u) {
    const float si = sqa[ti * 4 + u];
    float4 r;
    r.x = si + sqb[tj * 4 + 0] - 2.f * acc[u][0];
    r.y = si + sqb[tj * 4 + 1] - 2.f * acc[u][1];
    r.z = si + sqb[tj * 4 + 2] - 2.f * acc[u][2];
    r.w = si + sqb[tj * 4 + 3] - 2.f * acc[u][3];
    *(float4*)(d2 + ((size_t)blockIdx.z * NPB + i0 + ti * 4 + u) * NPB + j0 + tj * 4) = r;
  }
}

// ---------------------------------------------------------------------------
// select: top-30 smallest per D2 row; 1 wave/query, 16 reg slots/lane.
// ---------------------------------------------------------------------------
__global__ __launch_bounds__(256)
void select_kernel(const float* __restrict__ d2, int b0, int* __restrict__ idx) {
  const int wave = threadIdx.x >> 6, lane = threadIdx.x & 63;
  const int ql = blockIdx.x * 4 + wave;
  const int bl = ql >> 10;
  const int qnode = (b0 + bl) * NPB + (ql & (NPB - 1));
  const float* row = d2 + (size_t)ql * NPB;
  float d[16];
  #pragma unroll
  for (int i = 0; i < 16; ++i) d[i] = row[lane + (i << 6)];
  int* out = idx + (size_t)qnode * KNN_K;
  const int jbase = (b0 + bl) * NPB;
  #pragma unroll 1
  for (int k = 0; k < KNN_K; ++k) {
    float best = d[0]; int bi = 0;
    #pragma unroll
    for (int i = 1; i < 16; ++i) if (d[i] < best) { best = d[i]; bi = i; }
    int bj = lane + (bi << 6);
    #pragma unroll
    for (int o = 32; o > 0; o >>= 1) {
      const float ov = __shfl_down(best, o);
      const int   oj = __shfl_down(bj, o);
      if (ov < best) { best = ov; bj = oj; }
    }
    bj = __shfl(bj, 0);
    if (lane == 0) out[k] = jbase + bj;
    #pragma unroll
    for (int i = 0; i < 16; ++i) if (bj == lane + (i << 6)) d[i] = FINF;
  }
}

// ---------------------------------------------------------------------------
// edge (MFMA): per node, H[32 edges][64] @ W2[64][64] -> col-max over edges.
// One wave per node, no LDS. A-frags built in registers from bf16 as/vs;
// edges 30,31 are clamped duplicates of edge 29 (harmless under max).
// mfma_f32_16x16x32_bf16 convention: a[i]=A[l&15][(l>>4)*8+i],
// b[i]=B[(l>>4)*8+i][l&15], C reg r -> row=(l>>4)*4+r, col=l&15.
// ---------------------------------------------------------------------------
__global__ __launch_bounds__(256)
void edge_mfma_kernel(const ushort_t* __restrict__ as_,
                      const ushort_t* __restrict__ vs_,
                      const int* __restrict__ idx,
                      const float* __restrict__ W2, const float* __restrict__ b2,
                      float* __restrict__ xout, ushort_t* __restrict__ xbf,
                      int ldc) {
  const int lane = threadIdx.x & 63;
  const int node = blockIdx.x * 4 + (threadIdx.x >> 6);
  const int g = lane >> 4, r16 = lane & 15;

  // B fragments: W2[k][n] bf16, b[ks][nt]
  bf16x8 bf[2][4];
  #pragma unroll
  for (int ks = 0; ks < 2; ++ks)
    #pragma unroll
    for (int nt = 0; nt < 4; ++nt)
      #pragma unroll
      for (int i = 0; i < 8; ++i)
        bf[ks][nt][i] = (short)f2bf(W2[(ks * 32 + g * 8 + i) * 64 + nt * 16 + r16]);

  // as chunks for this node (8 bf16 per ks)
  float asf[2][8];
  {
    const ushort_t* ar = as_ + (size_t)node * 64;
    #pragma unroll
    for (int ks = 0; ks < 2; ++ks) {
      union { uint4 v; ushort_t s[8]; } u;
      u.v = *(const uint4*)(ar + ks * 32 + g * 8);
      #pragma unroll
      for (int i = 0; i < 8; ++i) asf[ks][i] = bf2f(u.s[i]);
    }
  }

  const int j0 = idx[(size_t)node * KNN_K + r16];                 // edges 0..15
  const int e1 = 16 + r16;
  const int j1 = idx[(size_t)node * KNN_K + (e1 < KNN_K ? e1 : KNN_K - 1)];

  f32x4 acc[2][4];
  #pragma unroll
  for (int mt = 0; mt < 2; ++mt)
    #pragma unroll
    for (int nt = 0; nt < 4; ++nt) acc[mt][nt] = (f32x4)(0.f);

  #pragma unroll
  for (int mt = 0; mt < 2; ++mt) {
    const int j = mt ? j1 : j0;
    const ushort_t* vr = vs_ + (size_t)j * 64;
    #pragma unroll
    for (int ks = 0; ks < 2; ++ks) {
      union { uint4 v; ushort_t s[8]; } u;
      u.v = *(const uint4*)(vr + ks * 32 + g * 8);
      bf16x8 af;
      #pragma unroll
      for (int i = 0; i < 8; ++i) {
        const float h = fmaxf(asf[ks][i] + bf2f(u.s[i]), 0.f);
        af[i] = (short)f2bf(h);
      }
      #pragma unroll
      for (int nt = 0; nt < 4; ++nt)
        acc[mt][nt] = __builtin_amdgcn_mfma_f32_16x16x32_bf16(af, bf[ks][nt], acc[mt][nt], 0, 0, 0);
    }
  }

  // col-max over 32 edge-rows: 4 regs (rows 4g..4g+3) then xor over g-groups
  float cm[4];
  #pragma unroll
  for (int nt = 0; nt < 4; ++nt) {
    float m0 = fmaxf(fmaxf(acc[0][nt][0], acc[0][nt][1]), fmaxf(acc[0][nt][2], acc[0][nt][3]));
    float m1 = fmaxf(fmaxf(acc[1][nt][0], acc[1][nt][1]), fmaxf(acc[1][nt][2], acc[1][nt][3]));
    float m = fmaxf(m0, m1);
    m = fmaxf(m, __shfl_xor(m, 16));
    m = fmaxf(m, __shfl_xor(m, 32));
    cm[nt] = m;
  }
  const float v = (g == 0) ? cm[0] : (g == 1) ? cm[1] : (g == 2) ? cm[2] : cm[3];
  const int c = g * 16 + r16;                       // == lane
  const float o = v + b2[c];
  xout[(size_t)node * ldc + c] = o;
  xbf [(size_t)node * 192 + c] = f2bf(o);
}

// ---------------------------------------------------------------------------
// wcvt: BT[n][k] = bf16(W[k][n]) — weights pre-transposed to bf16.
// ---------------------------------------------------------------------------
__global__ __launch_bounds__(256)
void wcvt_kernel(const float* __restrict__ W, ushort_t* __restrict__ BT,
                 int K, int N) {
  const int i = blockIdx.x * 256 + threadIdx.x;
  if (i >= N * K) return;
  const int n = i / K, k = i % K;
  BT[i] = f2bf(W[(size_t)k * N + n]);
}

// ---------------------------------------------------------------------------
// bf16 MFMA GEMM: C = relu?(A[M,K]bf16 @ B + bias). B passed as BT[N][K] bf16.
// BM=128 BN=128 BK=64, 4 waves (2x2), wave tile 64x64 (4x4 16x16 frags).
// LDS rows padded to 72 bf16 (144 B) -> conflict-light ds_read_b128.
// ---------------------------------------------------------------------------
template<bool RELU, typename CT>
__global__ __launch_bounds__(256)
void gemm_bf16_kernel(const ushort_t* __restrict__ A, int lda,
                      const ushort_t* __restrict__ BT, int ldb,
                      const float* __restrict__ bias,
                      CT* __restrict__ C, int ldc, int K) {
  __shared__ ushort_t As[128 * 72];
  __shared__ ushort_t Bs[128 * 72];
  const int tid = threadIdx.x;
  const int lane = tid & 63;
  const int g = lane >> 4, r16 = lane & 15;
  const int wv = tid >> 6, wm = wv >> 1, wn = wv & 1;
  const int bm = blockIdx.x * 128, bn = blockIdx.y * 128;

  f32x4 acc[4][4];
  #pragma unroll
  for (int mt = 0; mt < 4; ++mt)
    #pragma unroll
    for (int nt = 0; nt < 4; ++nt) acc[mt][nt] = (f32x4)(0.f);

  const int srow = tid >> 1, scq = (tid & 1) * 32;
  for (int k0 = 0; k0 < K; k0 += 64) {
    const ushort_t* ap = A + (size_t)(bm + srow) * lda + k0 + scq;
    const ushort_t* bp = BT + (size_t)(bn + srow) * ldb + k0 + scq;
    uint4 av0 = *(const uint4*)(ap);      uint4 av1 = *(const uint4*)(ap + 8);
    uint4 av2 = *(const uint4*)(ap + 16); uint4 av3 = *(const uint4*)(ap + 24);
    uint4 bv0 = *(const uint4*)(bp);      uint4 bv1 = *(const uint4*)(bp + 8);
    uint4 bv2 = *(const uint4*)(bp + 16); uint4 bv3 = *(const uint4*)(bp + 24);
    __syncthreads();
    *(uint4*)(As + srow * 72 + scq +  0) = av0;
    *(uint4*)(As + srow * 72 + scq +  8) = av1;
    *(uint4*)(As + srow * 72 + scq + 16) = av2;
    *(uint4*)(As + srow * 72 + scq + 24) = av3;
    *(uint4*)(Bs + srow * 72 + scq +  0) = bv0;
    *(uint4*)(Bs + srow * 72 + scq +  8) = bv1;
    *(uint4*)(Bs + srow * 72 + scq + 16) = bv2;
    *(uint4*)(Bs + srow * 72 + scq + 24) = bv3;
    __syncthreads();
    #pragma unroll
    for (int ks = 0; ks < 2; ++ks) {
      bf16x8 a[4], b[4];
      #pragma unroll
      for (int mt = 0; mt < 4; ++mt)
        a[mt] = *(const bf16x8*)(As + (wm * 64 + mt * 16 + r16) * 72 + ks * 32 + g * 8);
      #pragma unroll
      for (int nt = 0; nt < 4; ++nt)
        b[nt] = *(const bf16x8*)(Bs + (wn * 64 + nt * 16 + r16) * 72 + ks * 32 + g * 8);
      #pragma unroll
      for (int mt = 0; mt < 4; ++mt)
        #pragma unroll
        for (int nt = 0; nt < 4; ++nt)
          acc[mt][nt] = __builtin_amdgcn_mfma_f32_16x16x32_bf16(a[mt], b[nt], acc[mt][nt], 0, 0, 0);
    }
  }

  #pragma unroll
  for (int nt = 0; nt < 4; ++nt) {
    const int col = bn + wn * 64 + nt * 16 + r16;
    const float bv = bias[col];
    #pragma unroll
    for (int mt = 0; mt < 4; ++mt) {
      #pragma unroll
      for (int r = 0; r < 4; ++r) {
        const int row = bm + wm * 64 + mt * 16 + g * 4 + r;
        float val = acc[mt][nt][r] + bv;
        if (RELU) val = fmaxf(val, 0.f);
        if constexpr (sizeof(CT) == 2) C[(size_t)row * ldc + col] = f2bf(val);
        else                           C[(size_t)row * ldc + col] = val;
      }
    }
  }
}

// ---------------------------------------------------------------------------
// g4: logits = h3[row](bf16) @ W4[128,2] + b4 ; log_softmax. 1 wave/row.
// ---------------------------------------------------------------------------
__global__ __launch_bounds__(64)
void g4_kernel(const ushort_t* __restrict__ h3, const float* __restrict__ W4,
               const float* __restrict__ b4, float* __restrict__ seg) {
  const int row = blockIdx.x;
  const int lane = threadIdx.x;
  const ushort_t* hr = h3 + (size_t)row * 128;
  float p0 = 0.f, p1 = 0.f;
  #pragma unroll
  for (int h = 0; h < 2; ++h) {
    const int r = lane + h * 64;
    const float hv = bf2f(hr[r]);
    p0 += hv * W4[r * 2 + 0];
    p1 += hv * W4[r * 2 + 1];
  }
  #pragma unroll
  for (int o = 32; o > 0; o >>= 1) { p0 += __shfl_down(p0, o); p1 += __shfl_down(p1, o); }
  if (lane == 0) {
    const float l0 = p0 + b4[0], l1 = p1 + b4[1];
    const float mx = fmaxf(l0, l1);
    const float lse = mx + logf(expf(l0 - mx) + expf(l1 - mx));
    seg[(size_t)row * 2 + 0] = l0 - lse;
    seg[(size_t)row * 2 + 1] = l1 - lse;
  }
}

// ---------------------------------------------------------------------------
// wrapper: per event: y = relu(flat @ mW1 + mb1) @ mW2 + mb2 ; log_softmax.
// ---------------------------------------------------------------------------
__global__ __launch_bounds__(256)
void wrapper_kernel(const float* __restrict__ seg, const float* __restrict__ W1,
                    const float* __restrict__ b1, const float* __restrict__ W2,
                    const float* __restrict__ b2, float* __restrict__ out) {
  __shared__ float fl[NPB * 2];
  __shared__ float y1[100];
  __shared__ float l2[2];
  const int b = blockIdx.x, tid = threadIdx.x;
  for (int i = tid; i < NPB * 2; i += 256) fl[i] = seg[(size_t)b * NPB * 2 + i];
  __syncthreads();
  if (tid < 100) {
    float acc = b1[tid];
    for (int r = 0; r < NPB * 2; ++r) acc += fl[r] * W1[(size_t)r * 100 + tid];
    y1[tid] = fmaxf(acc, 0.f);
  }
  __syncthreads();
  if (tid < 2) {
    float acc = b2[tid];
    for (int j = 0; j < 100; ++j) acc += y1[j] * W2[j * 2 + tid];
    l2[tid] = acc;
  }
  __syncthreads();
  if (tid == 0) {
    const float l0 = l2[0], l1 = l2[1];
    const float mx = fmaxf(l0, l1);
    const float lse = mx + logf(expf(l0 - mx) + expf(l1 - mx));
    out[b * 2 + 0] = l0 - lse;
    out[b * 2 + 1] = l1 - lse;
  }
}

// ---------------------------------------------------------------------------
extern "C" void kernel_launch(void* const* d_in, const int* in_sizes, int n_in,
                              void* d_out, int out_size, void* d_ws, size_t ws_size,
                              hipStream_t stream) {
  const float* pos   = (const float*)d_in[0];
  const float* c1_W1 = (const float*)d_in[3];
  const float* c1_b1 = (const float*)d_in[4];
  const float* c1_s  = (const float*)d_in[5];
  const float* c1_t  = (const float*)d_in[6];
  const float* c1_W2 = (const float*)d_in[7];
  const float* c1_b2 = (const float*)d_in[8];
  const float* c2_W1 = (const float*)d_in[9];
  const float* c2_b1 = (const float*)d_in[10];
  const float* c2_s  = (const float*)d_in[11];
  const float* c2_t  = (const float*)d_in[12];
  const float* c2_W2 = (const float*)d_in[13];
  const float* c2_b2 = (const float*)d_in[14];
  const float* c3_W1 = (const float*)d_in[15];
  const float* c3_b1 = (const float*)d_in[16];
  const float* c3_s  = (const float*)d_in[17];
  const float* c3_t  = (const float*)d_in[18];
  const float* c3_W2 = (const float*)d_in[19];
  const float* c3_b2 = (const float*)d_in[20];
  const float* h_W1  = (const float*)d_in[21];
  const float* h_b1  = (const float*)d_in[22];
  const float* h_W2  = (const float*)d_in[23];
  const float* h_b2  = (const float*)d_in[24];
  const float* h_W3  = (const float*)d_in[25];
  const float* h_b3  = (const float*)d_in[26];
  const float* h_W4  = (const float*)d_in[27];
  const float* h_b4  = (const float*)d_in[28];
  const float* m_W1  = (const float*)d_in[29];
  const float* m_b1  = (const float*)d_in[30];
  const float* m_W2  = (const float*)d_in[31];
  const float* m_b2  = (const float*)d_in[32];

  float* ws = (float*)d_ws;
  size_t off = 0;
  auto alloc = [&](size_t n) {
    float* p = ws + off;
    off += (n + 63) & ~(size_t)63;
    return p;
  };
  float*    xfeat = alloc((size_t)NTOT * 192);            // f32 (kNN path)
  ushort_t* xbf   = (ushort_t*)alloc((size_t)NTOT * 96);  // bf16 mirror (gemm A)
  int*      idx   = (int*)alloc((size_t)NTOT * KNN_K);
  ushort_t* asb   = (ushort_t*)alloc((size_t)NTOT * 32);
  ushort_t* vsb   = (ushort_t*)alloc((size_t)NTOT * 32);
  float*    sqb   = alloc(NTOT);
  float*    seg   = alloc((size_t)NTOT * 2);
  ushort_t* BT1   = (ushort_t*)alloc(1024 * 192 / 2);
  ushort_t* BT2   = (ushort_t*)alloc(256 * 1024 / 2);
  ushort_t* BT3   = (ushort_t*)alloc(128 * 256 / 2);

  // Union region: d2 (knn phase) aliases h1/h2/h3 (head phase).
  const size_t totf = ws_size / 4;
  const size_t avail = (totf > off + 1024) ? (totf - off - 1024) : 0;
  int NBC = 32;
  while (NBC > 1 && (size_t)NBC * NPB * NPB > avail) NBC >>= 1;
  int CH = 1;
  while (CH < 256 && (size_t)(NTOT / CH) * 704 > avail) CH <<= 1;
  const int CR = NTOT / CH;
  float* d2buf = ws + off;
  ushort_t* h1 = (ushort_t*)d2buf;
  ushort_t* h2 = h1 + (size_t)CR * 1024;
  ushort_t* h3 = h2 + (size_t)CR * 256;

  // weights -> bf16 transposed (deterministic, every launch)
  wcvt_kernel<<<(192 * 1024 + 255) / 256, 256, 0, stream>>>(h_W1, BT1, 192, 1024);
  wcvt_kernel<<<(1024 * 256 + 255) / 256, 256, 0, stream>>>(h_W2, BT2, 1024, 256);
  wcvt_kernel<<<(256 * 128 + 255) / 256, 256, 0, stream>>>(h_W3, BT3, 256, 128);

  auto run_knn = [&](const float* x, int lda, int D) {
    for (int b0 = 0; b0 < NB; b0 += NBC) {
      if (D == 7) {
        dist_kernel<7><<<dim3(16, 16, NBC), 256, 0, stream>>>(x, lda, sqb, d2buf, b0);
      } else {
        dist_kernel<64><<<dim3(16, 16, NBC), 256, 0, stream>>>(x, lda, sqb, d2buf, b0);
      }
      select_kernel<<<(NBC * NPB) / 4, 256, 0, stream>>>(d2buf, b0, idx);
    }
  };

  // ---- conv1 (pos, D=7) -> cols 0..63
  node_pre_kernel<7><<<NTOT / 4, 256, 0, stream>>>(pos, 7, c1_W1, c1_b1, c1_s, c1_t, asb, vsb, sqb);
  run_knn(pos, 7, 7);
  edge_mfma_kernel<<<NTOT / 4, 256, 0, stream>>>(asb, vsb, idx, c1_W2, c1_b2, xfeat + 0, xbf + 0, 192);
  // ---- conv2 (x1, D=64) -> cols 64..127
  node_pre_kernel<64><<<NTOT / 4, 256, 0, stream>>>(xfeat + 0, 192, c2_W1, c2_b1, c2_s, c2_t, asb, vsb, sqb);
  run_knn(xfeat + 0, 192, 64);
  edge_mfma_kernel<<<NTOT / 4, 256, 0, stream>>>(asb, vsb, idx, c2_W2, c2_b2, xfeat + 64, xbf + 64, 192);
  // ---- conv3 (x2, D=64) -> cols 128..191
  node_pre_kernel<64><<<NTOT / 4, 256, 0, stream>>>(xfeat + 64, 192, c3_W1, c3_b1, c3_s, c3_t, asb, vsb, sqb);
  run_knn(xfeat + 64, 192, 64);
  edge_mfma_kernel<<<NTOT / 4, 256, 0, stream>>>(asb, vsb, idx, c3_W2, c3_b2, xfeat + 128, xbf + 128, 192);

  // ---- head MLP (bf16 MFMA, chunked) + per-node log_softmax
  for (int ch = 0; ch < CH; ++ch) {
    const ushort_t* Ax = xbf + (size_t)ch * CR * 192;
    gemm_bf16_kernel<true, ushort_t><<<dim3(CR / 128, 8), 256, 0, stream>>>(Ax, 192, BT1, 192, h_b1, h1, 1024, 192);
    gemm_bf16_kernel<true, ushort_t><<<dim3(CR / 128, 2), 256, 0, stream>>>(h1, 1024, BT2, 1024, h_b2, h2, 256, 1024);
    gemm_bf16_kernel<true, ushort_t><<<dim3(CR / 128, 1), 256, 0, stream>>>(h2, 256, BT3, 256, h_b3, h3, 128, 256);
    g4_kernel<<<CR, 64, 0, stream>>>(h3, h_W4, h_b4, seg + (size_t)ch * CR * 2);
  }

  // ---- wrapper MLP per event
  wrapper_kernel<<<NB, 256, 0, stream>>>(seg, m_W1, m_b1, m_W2, m_b2, (float*)d_out);
}